// Round 5
// baseline (377.170 us; speedup 1.0000x reference)
//
#include <hip/hip_runtime.h>

// VertexUpdate: out[i] = (b_i, x_i, b_i - sum_{e:src[e]=i} c_e)
//
// R1: device atomicAdd scatter -> 771 us; WRITE 500 MB.
// R4: radix binning, cursor scatter -> 640 us.
// R5: LDS counting-sort + linear copy-out -> 429 us.
// R6: TPB 1024, register-staged vector loads -> 401 us.
// R7: shuffle wave-scan (18 barriers -> 5) -> 390 us.
// R8: persistent blocks + cross-barrier register prefetch -> FLAT
//     (VGPR=32 later proved the prefetch was compiled away).
// R9: 8-replica alloc counters (cross-XCD atomic contention) -> 373 us.
// R10: single-shot blocks TPB 512 / TILE 4096, 4 blocks/CU -> 367 us;
//      partition 99.5 us @ 30% HBM, VALU 12%, occ 73%.
// Forensics: (a) VGPR_Count=20 -> eattr loads AGAIN sunk to the scatter
//      phase (can't hold 24 data regs in 20); exposed burst latency after
//      B3 every block. (b) dur_us == partition + 267 us (+-2) across ALL
//      rounds -> aggregate (<99 us) + fixed overhead never responded.
// R11: (a) partition: keepalive asm pins loaded values -> loads issue at
//      block start, materialize once after B0, live through scatter.
//      Check: VGPR 20 -> ~44. (b) aggregate: masked 8-segment interleaved
//      loads (8 independent 16B loads in flight/thread), SGPR counts,
//      launch_bounds(1024,8), odd-tails on threads 0..7.
//      Predict: partition ~89; total ~330 if aggregate visible in the
//      timed path, ~357 if not (that tells us where the 267 us lives).

#define BSHIFT 11
#define BSIZE (1 << BSHIFT)      // 2048 vertices per bucket
#define NBUCK_PAD 512            // padded bucket count (real: 489)
#define TILE 4096
#define TPB 512                  // == NBUCK_PAD: one bucket per thread
#define NREP 8                   // replica sets (one per XCD)

// Barrier that does NOT drain vmcnt: LDS ordering only.
#define BARL() do { \
    asm volatile("s_waitcnt lgkmcnt(0)" ::: "memory"); \
    __builtin_amdgcn_s_barrier(); } while (0)

__global__ __launch_bounds__(TPB, 8)
void vu_partition(const int* __restrict__ src,
                  const float* __restrict__ eattr,
                  unsigned long long* __restrict__ pairs,
                  unsigned int* __restrict__ alloc,
                  int ne, int nbuck, int cap_r) {
    __shared__ unsigned long long sorted[TILE];   // 32 KB
    __shared__ unsigned int hist[NBUCK_PAD];      // becomes gbase after scan
    __shared__ unsigned int base_l[NBUCK_PAD];
    __shared__ unsigned int cursor[NBUCK_PAD];
    __shared__ unsigned int wsum[8];              // per-wave scan sums
    // total ~38.1 KB -> 4 blocks/CU (32 waves)

    const int t = threadIdx.x;
    const int rep = blockIdx.x & (NREP - 1);      // replica set (~XCD id)
    const int tile0 = blockIdx.x * TILE;
    int lim = ne - tile0; if (lim > TILE) lim = TILE;
    const bool full = (lim == TILE);

    // --- 1) issue all global loads FIRST (latency overlaps B0) ---
    int4 sa, sb;
    float c0, c1, c2, c3, c4, c5, c6, c7;
    if (full) {
        const int4* s4 = (const int4*)(src + tile0) + 2 * t;
        sa = s4[0];                               // edges 8t..8t+3
        sb = s4[1];                               // edges 8t+4..8t+7
        const float4* e4 = (const float4*)(eattr + 2 * (size_t)tile0) + 4 * t;
        float4 e0 = e4[0], e1 = e4[1], e2 = e4[2], e3 = e4[3];
        c0 = e0.y; c1 = e0.w; c2 = e1.y; c3 = e1.w;
        c4 = e2.y; c5 = e2.w; c6 = e3.y; c7 = e3.w;
    }
    hist[t] = 0u;                                 // TPB == NBUCK_PAD
    BARL();                                       // B0: hist zeroed

    if (full) {
        // keepalive: force ALL loaded values materialized HERE and live
        // through the scatter phase (defeats compiler load-sinking, the
        // R8/R10 failure mode; verify via VGPR_Count ~44, was 20).
        asm volatile("" ::
            "v"(sa.x), "v"(sa.y), "v"(sa.z), "v"(sa.w),
            "v"(sb.x), "v"(sb.y), "v"(sb.z), "v"(sb.w),
            "v"(c0), "v"(c1), "v"(c2), "v"(c3),
            "v"(c4), "v"(c5), "v"(c6), "v"(c7));
        atomicAdd(&hist[((unsigned)sa.x) >> BSHIFT], 1u);
        atomicAdd(&hist[((unsigned)sa.y) >> BSHIFT], 1u);
        atomicAdd(&hist[((unsigned)sa.z) >> BSHIFT], 1u);
        atomicAdd(&hist[((unsigned)sa.w) >> BSHIFT], 1u);
        atomicAdd(&hist[((unsigned)sb.x) >> BSHIFT], 1u);
        atomicAdd(&hist[((unsigned)sb.y) >> BSHIFT], 1u);
        atomicAdd(&hist[((unsigned)sb.z) >> BSHIFT], 1u);
        atomicAdd(&hist[((unsigned)sb.w) >> BSHIFT], 1u);
    } else {
        for (int i = t; i < lim; i += TPB)
            atomicAdd(&hist[((unsigned)src[tile0 + i]) >> BSHIFT], 1u);
    }
    BARL();                                       // B1: hist complete

    unsigned int mycnt = hist[t];
    // replica-local allocation atomic; latency hides under the scan.
    unsigned int gb = 0u;
    if (t < nbuck && mycnt)
        gb = atomicAdd(&alloc[rep * NBUCK_PAD + t], mycnt);

    // --- 2) exclusive scan over 512 buckets (shuffle wave-scan) ---
    unsigned int x = mycnt;
    #pragma unroll
    for (int off = 1; off < 64; off <<= 1) {
        unsigned int v = __shfl_up(x, off, 64);
        if ((t & 63) >= off) x += v;
    }
    if ((t & 63) == 63) wsum[t >> 6] = x;
    BARL();                                       // B2: wsum ready

    unsigned int wx = 0u;
    int wid = t >> 6;
    #pragma unroll
    for (int k = 0; k < 7; ++k) {                 // redundant per-thread prefix
        unsigned int w = wsum[k];
        if (k < wid) wx += w;
    }
    unsigned int excl = x + wx - mycnt;
    base_l[t] = excl;
    cursor[t] = excl;
    hist[t] = gb;                                 // hist[] now holds gbase
    BARL();                                       // B3: cursors ready

    // --- 3) scatter into LDS sorted by bucket (all data in registers) ---
#define VU_SCAT(sv, cv) do { \
        unsigned int q_ = ((unsigned)(sv)) >> BSHIFT; \
        unsigned int pos_ = atomicAdd(&cursor[q_], 1u); \
        sorted[pos_] = ((unsigned long long)__float_as_uint(cv) << 32) \
                       | (unsigned)(sv); } while (0)
    if (full) {
        VU_SCAT(sa.x, c0); VU_SCAT(sa.y, c1);
        VU_SCAT(sa.z, c2); VU_SCAT(sa.w, c3);
        VU_SCAT(sb.x, c4); VU_SCAT(sb.y, c5);
        VU_SCAT(sb.z, c6); VU_SCAT(sb.w, c7);
    } else {
        for (int i = t; i < lim; i += TPB) {
            int e = tile0 + i;
            int s = src[e];
            float2 ec = ((const float2*)eattr)[e];
            VU_SCAT(s, ec.y);
        }
    }
#undef VU_SCAT
    BARL();                                       // B4: sorted ready

    // --- 4) linear copy-out into this block's replica region ---
    for (int i = t; i < lim; i += TPB) {
        unsigned long long p = sorted[i];
        unsigned int q = ((unsigned int)p) >> BSHIFT;
        unsigned int seg = (q << 3) + (unsigned int)rep;      // q*NREP+rep
        unsigned int dst = seg * (unsigned int)cap_r + hist[q]
                         + ((unsigned int)i - base_l[q]);
        unsigned int hi = seg * (unsigned int)cap_r + (unsigned int)cap_r - 1u;
        if (dst > hi) dst = hi;                    // OOB guard (never fires)
        pairs[dst] = p;
    }
}

__global__ __launch_bounds__(1024, 8)
void vu_aggregate(const unsigned long long* __restrict__ pairs,
                  const unsigned int* __restrict__ alloc,
                  const float* __restrict__ vattr,
                  float* __restrict__ out,
                  int nv, int cap_r) {
    __shared__ float acc[BSIZE];                   // 8 KB
    __shared__ float obuf[BSIZE * 3];              // 24 KB
    int q = blockIdx.x;
    int t = threadIdx.x;
    acc[t] = 0.0f;
    acc[t + 1024] = 0.0f;

    // early vattr loads: latency hides under the pair loops
    int v0 = q << BSHIFT;
    int iv0 = v0 + t, iv1 = v0 + t + 1024;
    float2 va0 = make_float2(0.f, 0.f), va1 = make_float2(0.f, 0.f);
    if (iv0 < nv) va0 = ((const float2*)vattr)[iv0];
    if (iv1 < nv) va1 = ((const float2*)vattr)[iv1];

    // segment counts (block-uniform -> SGPRs) and base pointers
    unsigned int cnts[NREP], n2r[NREP];
    unsigned int n2max = 0u;
    #pragma unroll
    for (int r = 0; r < NREP; ++r) {
        unsigned int c = alloc[r * NBUCK_PAD + q];
        if (c > (unsigned int)cap_r) c = (unsigned int)cap_r;
        cnts[r] = c;
        n2r[r] = c >> 1;
        if (n2r[r] > n2max) n2max = n2r[r];
    }
    const ulonglong2* p20 = (const ulonglong2*)(pairs + (size_t)(q * NREP + 0) * cap_r);
    const ulonglong2* p21 = (const ulonglong2*)(pairs + (size_t)(q * NREP + 1) * cap_r);
    const ulonglong2* p22 = (const ulonglong2*)(pairs + (size_t)(q * NREP + 2) * cap_r);
    const ulonglong2* p23 = (const ulonglong2*)(pairs + (size_t)(q * NREP + 3) * cap_r);
    const ulonglong2* p24 = (const ulonglong2*)(pairs + (size_t)(q * NREP + 4) * cap_r);
    const ulonglong2* p25 = (const ulonglong2*)(pairs + (size_t)(q * NREP + 5) * cap_r);
    const ulonglong2* p26 = (const ulonglong2*)(pairs + (size_t)(q * NREP + 6) * cap_r);
    const ulonglong2* p27 = (const ulonglong2*)(pairs + (size_t)(q * NREP + 7) * cap_r);
    __syncthreads();

#define VU_ACC(v64) do { \
        atomicAdd(&acc[((unsigned int)(v64)) & (BSIZE - 1)], \
                  __uint_as_float((unsigned int)((v64) >> 32))); } while (0)

    // 8-segment interleave: 8 independent 16B loads in flight per iter
    for (unsigned int i = t; i < n2max; i += 1024u) {
        bool m0 = i < n2r[0], m1 = i < n2r[1], m2 = i < n2r[2], m3 = i < n2r[3];
        bool m4 = i < n2r[4], m5 = i < n2r[5], m6 = i < n2r[6], m7 = i < n2r[7];
        ulonglong2 w0, w1, w2, w3, w4, w5, w6, w7;
        if (m0) w0 = p20[i];
        if (m1) w1 = p21[i];
        if (m2) w2 = p22[i];
        if (m3) w3 = p23[i];
        if (m4) w4 = p24[i];
        if (m5) w5 = p25[i];
        if (m6) w6 = p26[i];
        if (m7) w7 = p27[i];
        if (m0) { VU_ACC(w0.x); VU_ACC(w0.y); }
        if (m1) { VU_ACC(w1.x); VU_ACC(w1.y); }
        if (m2) { VU_ACC(w2.x); VU_ACC(w2.y); }
        if (m3) { VU_ACC(w3.x); VU_ACC(w3.y); }
        if (m4) { VU_ACC(w4.x); VU_ACC(w4.y); }
        if (m5) { VU_ACC(w5.x); VU_ACC(w5.y); }
        if (m6) { VU_ACC(w6.x); VU_ACC(w6.y); }
        if (m7) { VU_ACC(w7.x); VU_ACC(w7.y); }
    }
    // odd tails: one per segment, 8 threads in parallel
    if (t < NREP) {
        unsigned int cnt = cnts[t];
        if (cnt & 1u) {
            const unsigned long long* p =
                pairs + (size_t)(q * NREP + t) * (size_t)cap_r;
            unsigned long long v = p[cnt - 1];
            VU_ACC(v);
        }
    }
#undef VU_ACC
    __syncthreads();

    if (iv0 < nv) {
        obuf[3 * t + 0] = va0.x;
        obuf[3 * t + 1] = va0.y;
        obuf[3 * t + 2] = va0.x - acc[t];
    }
    {
        int i2 = t + 1024;
        if (iv1 < nv) {
            obuf[3 * i2 + 0] = va1.x;
            obuf[3 * i2 + 1] = va1.y;
            obuf[3 * i2 + 2] = va1.x - acc[i2];
        }
    }
    __syncthreads();

    // coalesced float4 write of the bucket's contiguous out-slice
    long fbase = (long)q * (BSIZE * 3);
    int nfl = 3 * nv - (int)fbase;
    if (nfl > BSIZE * 3) nfl = BSIZE * 3;
    if (nfl > 0) {
        float4* o4 = (float4*)(out + fbase);       // fbase mult of 4
        const float4* s4 = (const float4*)obuf;
        int n4 = nfl >> 2;
        for (int j = t; j < n4; j += 1024) o4[j] = s4[j];
        for (int j = (n4 << 2) + t; j < nfl; j += 1024) out[fbase + j] = obuf[j];
    }
}

// ---- fallback (round-1 path, 961 us) if ws is too small ----
__global__ void vu_init_kernel(const float* __restrict__ vattr,
                               float* __restrict__ out, int n) {
    int i = blockIdx.x * blockDim.x + threadIdx.x;
    if (i < n) {
        float2 v = ((const float2*)vattr)[i];
        out[3 * i + 0] = v.x;
        out[3 * i + 1] = v.y;
        out[3 * i + 2] = v.x;
    }
}

__global__ void vu_scatter_kernel(const int* __restrict__ src,
                                  const float* __restrict__ eattr,
                                  float* __restrict__ out, int ne) {
    int t = blockIdx.x * blockDim.x + threadIdx.x;
    int e0 = t * 4;
    if (e0 + 3 < ne) {
        int4 idx = ((const int4*)src)[t];
        float4 a = ((const float4*)eattr)[2 * t + 0];
        float4 b = ((const float4*)eattr)[2 * t + 1];
        atomicAdd(&out[3 * idx.x + 2], -a.y);
        atomicAdd(&out[3 * idx.y + 2], -a.w);
        atomicAdd(&out[3 * idx.z + 2], -b.y);
        atomicAdd(&out[3 * idx.w + 2], -b.w);
    } else {
        for (int e = e0; e < ne; ++e)
            atomicAdd(&out[3 * src[e] + 2], -eattr[2 * e + 1]);
    }
}

extern "C" void kernel_launch(void* const* d_in, const int* in_sizes, int n_in,
                              void* d_out, int out_size, void* d_ws, size_t ws_size,
                              hipStream_t stream) {
    const float* vattr = (const float*)d_in[0];
    const int* edges = (const int*)d_in[1];   // (2, N_E); row 0 = src
    const float* eattr = (const float*)d_in[2];
    float* out = (float*)d_out;

    int nv = in_sizes[0] / 2;   // 1,000,000
    int ne = in_sizes[2] / 2;   // 16,000,000

    int nbuck = (nv + BSIZE - 1) >> BSHIFT;          // 489
    int mean_r = ne / nbuck / NREP;                  // ~4090
    int cap_r = mean_r + mean_r / 8;                 // ~+12.5% (~8 sigma)
    cap_r = (cap_r + 15) & ~15;                      // 4608

    size_t alloc_bytes = (size_t)NREP * NBUCK_PAD * 4;   // 16 KB
    size_t pair_bytes = (size_t)nbuck * NREP * (size_t)cap_r * 8ull;
    size_t need = alloc_bytes + pair_bytes;          // ~144 MB

    if (ws_size >= need && nbuck <= NBUCK_PAD) {
        unsigned int* alloc = (unsigned int*)d_ws;
        unsigned long long* pairs = (unsigned long long*)((char*)d_ws + alloc_bytes);
        (void)hipMemsetAsync(alloc, 0, alloc_bytes, stream);

        int nt_tiles = (ne + TILE - 1) / TILE;       // 3907
        vu_partition<<<nt_tiles, TPB, 0, stream>>>(edges, eattr, pairs, alloc,
                                                   ne, nbuck, cap_r);
        vu_aggregate<<<nbuck, 1024, 0, stream>>>(pairs, alloc, vattr, out,
                                                 nv, cap_r);
    } else {
        int threads = 256;
        int blocks = (nv + threads - 1) / threads;
        vu_init_kernel<<<blocks, threads, 0, stream>>>(vattr, out, nv);
        int nt = (ne + 3) / 4;
        blocks = (nt + threads - 1) / threads;
        vu_scatter_kernel<<<blocks, threads, 0, stream>>>(edges, eattr, out, ne);
    }
}

// Round 6
// 371.664 us; speedup vs baseline: 1.0148x; 1.0148x over previous
//
#include <hip/hip_runtime.h>

// VertexUpdate: out[i] = (b_i, x_i, b_i - sum_{e:src[e]=i} c_e)
//
// R1: device atomicAdd scatter -> 771 us. R4: radix binning -> 640 us.
// R5: LDS counting-sort -> 429 us. R6: register-staged loads -> 401 us.
// R7: shuffle wave-scan -> 390 us. R8: cross-barrier prefetch -> FLAT
//     (compiled away). R9: 8-replica alloc counters -> 373 us.
// R10: single-shot TPB 512 / TILE 4096, 4 blocks/CU -> 367 us.
// R11: (a) input-only keepalive FAILED: VGPR stayed 20 -> compiler
//      rematerialized loads at scatter (L2 reloads, FETCH flat). Wrong
//      idiom: "v" pins completion, not liveness.
//      (b) aggregate measured: 99.5 us @ VALU 1.9%, HBM 10%, VGPR 24.
//      VGPR=24 < 32 needed for 8 ulonglong2 -> masked loads were
//      SERIALIZED by exec-mask branches (16 x ~400cy exposed per thread).
// R12: (a) partition "+v" keepalive (read-write: post-asm values must be
//      carried to last use). Check: VGPR 20 -> ~44.
//      (b) partition: hist[t]=gb deferred to post-scatter (pre-B4) ->
//      alloc atomic RTT hides under scan+scatter, not just scan.
//      (c) aggregate: BRANCH-FREE 8-way MLP. Loads unconditional (always
//      in-bounds inside cap_r region); mask moves to the addend
//      (add = m ? val : 0.0f; +0.0 to a garbage-indexed slot is a no-op,
//      index &2047 always safe). Check: VGPR 24 -> ~52.
//      Predict: aggregate ~45-60, partition ~88, total ~310-330.

#define BSHIFT 11
#define BSIZE (1 << BSHIFT)      // 2048 vertices per bucket
#define NBUCK_PAD 512            // padded bucket count (real: 489)
#define TILE 4096
#define TPB 512                  // == NBUCK_PAD: one bucket per thread
#define NREP 8                   // replica sets (one per XCD)

// Barrier that does NOT drain vmcnt: LDS ordering only.
#define BARL() do { \
    asm volatile("s_waitcnt lgkmcnt(0)" ::: "memory"); \
    __builtin_amdgcn_s_barrier(); } while (0)

__global__ __launch_bounds__(TPB, 8)
void vu_partition(const int* __restrict__ src,
                  const float* __restrict__ eattr,
                  unsigned long long* __restrict__ pairs,
                  unsigned int* __restrict__ alloc,
                  int ne, int nbuck, int cap_r) {
    __shared__ unsigned long long sorted[TILE];   // 32 KB
    __shared__ unsigned int hist[NBUCK_PAD];      // becomes gbase after scatter
    __shared__ unsigned int base_l[NBUCK_PAD];
    __shared__ unsigned int cursor[NBUCK_PAD];
    __shared__ unsigned int wsum[8];              // per-wave scan sums
    // total ~38.1 KB -> 4 blocks/CU (32 waves)

    const int t = threadIdx.x;
    const int rep = blockIdx.x & (NREP - 1);      // replica set (~XCD id)
    const int tile0 = blockIdx.x * TILE;
    int lim = ne - tile0; if (lim > TILE) lim = TILE;
    const bool full = (lim == TILE);

    // --- 1) issue all global loads FIRST (latency overlaps B0) ---
    int4 sa, sb;
    float c0, c1, c2, c3, c4, c5, c6, c7;
    if (full) {
        const int4* s4 = (const int4*)(src + tile0) + 2 * t;
        sa = s4[0];                               // edges 8t..8t+3
        sb = s4[1];                               // edges 8t+4..8t+7
        const float4* e4 = (const float4*)(eattr + 2 * (size_t)tile0) + 4 * t;
        float4 e0 = e4[0], e1 = e4[1], e2 = e4[2], e3 = e4[3];
        c0 = e0.y; c1 = e0.w; c2 = e1.y; c3 = e1.w;
        c4 = e2.y; c5 = e2.w; c6 = e3.y; c7 = e3.w;
    }
    hist[t] = 0u;                                 // TPB == NBUCK_PAD
    BARL();                                       // B0: hist zeroed

    if (full) {
        // "+v" keepalive: values are read AND (nominally) written by the
        // asm -> compiler cannot rematerialize them from the original
        // loads; they must stay live in VGPRs through the scatter.
        // Attribution check: VGPR_Count ~44 (was 20).
        asm volatile("" :
            "+v"(sa.x), "+v"(sa.y), "+v"(sa.z), "+v"(sa.w),
            "+v"(sb.x), "+v"(sb.y), "+v"(sb.z), "+v"(sb.w),
            "+v"(c0), "+v"(c1), "+v"(c2), "+v"(c3),
            "+v"(c4), "+v"(c5), "+v"(c6), "+v"(c7));
        atomicAdd(&hist[((unsigned)sa.x) >> BSHIFT], 1u);
        atomicAdd(&hist[((unsigned)sa.y) >> BSHIFT], 1u);
        atomicAdd(&hist[((unsigned)sa.z) >> BSHIFT], 1u);
        atomicAdd(&hist[((unsigned)sa.w) >> BSHIFT], 1u);
        atomicAdd(&hist[((unsigned)sb.x) >> BSHIFT], 1u);
        atomicAdd(&hist[((unsigned)sb.y) >> BSHIFT], 1u);
        atomicAdd(&hist[((unsigned)sb.z) >> BSHIFT], 1u);
        atomicAdd(&hist[((unsigned)sb.w) >> BSHIFT], 1u);
    } else {
        for (int i = t; i < lim; i += TPB)
            atomicAdd(&hist[((unsigned)src[tile0 + i]) >> BSHIFT], 1u);
    }
    BARL();                                       // B1: hist complete

    unsigned int mycnt = hist[t];
    // replica-local allocation atomic; result not needed until pre-B4
    // (hist[t]=gb moved post-scatter) -> RTT hides under scan+scatter.
    unsigned int gb = 0u;
    if (t < nbuck && mycnt)
        gb = atomicAdd(&alloc[rep * NBUCK_PAD + t], mycnt);

    // --- 2) exclusive scan over 512 buckets (shuffle wave-scan) ---
    unsigned int x = mycnt;
    #pragma unroll
    for (int off = 1; off < 64; off <<= 1) {
        unsigned int v = __shfl_up(x, off, 64);
        if ((t & 63) >= off) x += v;
    }
    if ((t & 63) == 63) wsum[t >> 6] = x;
    BARL();                                       // B2: wsum ready

    unsigned int wx = 0u;
    int wid = t >> 6;
    #pragma unroll
    for (int k = 0; k < 7; ++k) {                 // redundant per-thread prefix
        unsigned int w = wsum[k];
        if (k < wid) wx += w;
    }
    unsigned int excl = x + wx - mycnt;
    base_l[t] = excl;
    cursor[t] = excl;
    BARL();                                       // B3: cursors ready

    // --- 3) scatter into LDS sorted by bucket (alloc atomic in flight) ---
#define VU_SCAT(sv, cv) do { \
        unsigned int q_ = ((unsigned)(sv)) >> BSHIFT; \
        unsigned int pos_ = atomicAdd(&cursor[q_], 1u); \
        sorted[pos_] = ((unsigned long long)__float_as_uint(cv) << 32) \
                       | (unsigned)(sv); } while (0)
    if (full) {
        VU_SCAT(sa.x, c0); VU_SCAT(sa.y, c1);
        VU_SCAT(sa.z, c2); VU_SCAT(sa.w, c3);
        VU_SCAT(sb.x, c4); VU_SCAT(sb.y, c5);
        VU_SCAT(sb.z, c6); VU_SCAT(sb.w, c7);
    } else {
        for (int i = t; i < lim; i += TPB) {
            int e = tile0 + i;
            int s = src[e];
            float2 ec = ((const float2*)eattr)[e];
            VU_SCAT(s, ec.y);
        }
    }
#undef VU_SCAT
    // publish gbase as late as possible: hist[] has no readers between
    // B3 and B4 (mycnt reads were pre-B2), so this is race-free.
    hist[t] = gb;                                 // waits on atomic HERE
    BARL();                                       // B4: sorted + gbase ready

    // --- 4) linear copy-out into this block's replica region ---
    for (int i = t; i < lim; i += TPB) {
        unsigned long long p = sorted[i];
        unsigned int q = ((unsigned int)p) >> BSHIFT;
        unsigned int seg = (q << 3) + (unsigned int)rep;      // q*NREP+rep
        unsigned int dst = seg * (unsigned int)cap_r + hist[q]
                         + ((unsigned int)i - base_l[q]);
        unsigned int hi = seg * (unsigned int)cap_r + (unsigned int)cap_r - 1u;
        if (dst > hi) dst = hi;                    // OOB guard (never fires)
        pairs[dst] = p;
    }
}

__global__ __launch_bounds__(1024, 8)
void vu_aggregate(const unsigned long long* __restrict__ pairs,
                  const unsigned int* __restrict__ alloc,
                  const float* __restrict__ vattr,
                  float* __restrict__ out,
                  int nv, int cap_r) {
    __shared__ float acc[BSIZE];                   // 8 KB
    __shared__ float obuf[BSIZE * 3];              // 24 KB
    int q = blockIdx.x;
    int t = threadIdx.x;
    acc[t] = 0.0f;
    acc[t + 1024] = 0.0f;

    // early vattr loads: latency hides under the pair loops
    int v0 = q << BSHIFT;
    int iv0 = v0 + t, iv1 = v0 + t + 1024;
    float2 va0 = make_float2(0.f, 0.f), va1 = make_float2(0.f, 0.f);
    if (iv0 < nv) va0 = ((const float2*)vattr)[iv0];
    if (iv1 < nv) va1 = ((const float2*)vattr)[iv1];

    // segment counts (block-uniform -> SGPRs) and base pointers
    unsigned int cnts[NREP], n2r[NREP];
    unsigned int n2max = 0u;
    #pragma unroll
    for (int r = 0; r < NREP; ++r) {
        unsigned int c = alloc[r * NBUCK_PAD + q];
        if (c > (unsigned int)cap_r) c = (unsigned int)cap_r;
        cnts[r] = c;
        n2r[r] = c >> 1;
        if (n2r[r] > n2max) n2max = n2r[r];
    }
    const ulonglong2* p20 = (const ulonglong2*)(pairs + (size_t)(q * NREP + 0) * cap_r);
    const ulonglong2* p21 = (const ulonglong2*)(pairs + (size_t)(q * NREP + 1) * cap_r);
    const ulonglong2* p22 = (const ulonglong2*)(pairs + (size_t)(q * NREP + 2) * cap_r);
    const ulonglong2* p23 = (const ulonglong2*)(pairs + (size_t)(q * NREP + 3) * cap_r);
    const ulonglong2* p24 = (const ulonglong2*)(pairs + (size_t)(q * NREP + 4) * cap_r);
    const ulonglong2* p25 = (const ulonglong2*)(pairs + (size_t)(q * NREP + 5) * cap_r);
    const ulonglong2* p26 = (const ulonglong2*)(pairs + (size_t)(q * NREP + 6) * cap_r);
    const ulonglong2* p27 = (const ulonglong2*)(pairs + (size_t)(q * NREP + 7) * cap_r);
    __syncthreads();

    // Branch-free 8-segment MLP: loads are UNCONDITIONAL (i < n2max <=
    // cap_r/2, so reads stay inside the allocated cap_r region; slack
    // contains garbage). Masking moves to the addend: +0.0f into a
    // garbage-indexed (but in-range, &2047) slot is a no-op. No exec-mask
    // branches -> all 8 loads issue back-to-back (true MLP).
    // Attribution check: VGPR ~52 (was 24 = serialized).
#define VU_ACC2(w, r) do { \
        bool m_ = (i < n2r[r]); \
        float ax_ = m_ ? __uint_as_float((unsigned int)((w).x >> 32)) : 0.0f; \
        float ay_ = m_ ? __uint_as_float((unsigned int)((w).y >> 32)) : 0.0f; \
        atomicAdd(&acc[((unsigned int)(w).x) & (BSIZE - 1)], ax_); \
        atomicAdd(&acc[((unsigned int)(w).y) & (BSIZE - 1)], ay_); } while (0)

    for (unsigned int i = t; i < n2max; i += 1024u) {
        ulonglong2 w0 = p20[i], w1 = p21[i], w2 = p22[i], w3 = p23[i];
        ulonglong2 w4 = p24[i], w5 = p25[i], w6 = p26[i], w7 = p27[i];
        VU_ACC2(w0, 0); VU_ACC2(w1, 1); VU_ACC2(w2, 2); VU_ACC2(w3, 3);
        VU_ACC2(w4, 4); VU_ACC2(w5, 5); VU_ACC2(w6, 6); VU_ACC2(w7, 7);
    }
#undef VU_ACC2

    // odd tails: one per segment, 8 threads in parallel
    if (t < NREP) {
        unsigned int cnt = cnts[t];
        if (cnt & 1u) {
            const unsigned long long* p =
                pairs + (size_t)(q * NREP + t) * (size_t)cap_r;
            unsigned long long v = p[cnt - 1];
            atomicAdd(&acc[((unsigned int)v) & (BSIZE - 1)],
                      __uint_as_float((unsigned int)(v >> 32)));
        }
    }
    __syncthreads();

    if (iv0 < nv) {
        obuf[3 * t + 0] = va0.x;
        obuf[3 * t + 1] = va0.y;
        obuf[3 * t + 2] = va0.x - acc[t];
    }
    {
        int i2 = t + 1024;
        if (iv1 < nv) {
            obuf[3 * i2 + 0] = va1.x;
            obuf[3 * i2 + 1] = va1.y;
            obuf[3 * i2 + 2] = va1.x - acc[i2];
        }
    }
    __syncthreads();

    // coalesced float4 write of the bucket's contiguous out-slice
    long fbase = (long)q * (BSIZE * 3);
    int nfl = 3 * nv - (int)fbase;
    if (nfl > BSIZE * 3) nfl = BSIZE * 3;
    if (nfl > 0) {
        float4* o4 = (float4*)(out + fbase);       // fbase mult of 4
        const float4* s4 = (const float4*)obuf;
        int n4 = nfl >> 2;
        for (int j = t; j < n4; j += 1024) o4[j] = s4[j];
        for (int j = (n4 << 2) + t; j < nfl; j += 1024) out[fbase + j] = obuf[j];
    }
}

// ---- fallback (round-1 path, 961 us) if ws is too small ----
__global__ void vu_init_kernel(const float* __restrict__ vattr,
                               float* __restrict__ out, int n) {
    int i = blockIdx.x * blockDim.x + threadIdx.x;
    if (i < n) {
        float2 v = ((const float2*)vattr)[i];
        out[3 * i + 0] = v.x;
        out[3 * i + 1] = v.y;
        out[3 * i + 2] = v.x;
    }
}

__global__ void vu_scatter_kernel(const int* __restrict__ src,
                                  const float* __restrict__ eattr,
                                  float* __restrict__ out, int ne) {
    int t = blockIdx.x * blockDim.x + threadIdx.x;
    int e0 = t * 4;
    if (e0 + 3 < ne) {
        int4 idx = ((const int4*)src)[t];
        float4 a = ((const float4*)eattr)[2 * t + 0];
        float4 b = ((const float4*)eattr)[2 * t + 1];
        atomicAdd(&out[3 * idx.x + 2], -a.y);
        atomicAdd(&out[3 * idx.y + 2], -a.w);
        atomicAdd(&out[3 * idx.z + 2], -b.y);
        atomicAdd(&out[3 * idx.w + 2], -b.w);
    } else {
        for (int e = e0; e < ne; ++e)
            atomicAdd(&out[3 * src[e] + 2], -eattr[2 * e + 1]);
    }
}

extern "C" void kernel_launch(void* const* d_in, const int* in_sizes, int n_in,
                              void* d_out, int out_size, void* d_ws, size_t ws_size,
                              hipStream_t stream) {
    const float* vattr = (const float*)d_in[0];
    const int* edges = (const int*)d_in[1];   // (2, N_E); row 0 = src
    const float* eattr = (const float*)d_in[2];
    float* out = (float*)d_out;

    int nv = in_sizes[0] / 2;   // 1,000,000
    int ne = in_sizes[2] / 2;   // 16,000,000

    int nbuck = (nv + BSIZE - 1) >> BSHIFT;          // 489
    int mean_r = ne / nbuck / NREP;                  // ~4090
    int cap_r = mean_r + mean_r / 8;                 // ~+12.5% (~8 sigma)
    cap_r = (cap_r + 15) & ~15;                      // 4608

    size_t alloc_bytes = (size_t)NREP * NBUCK_PAD * 4;   // 16 KB
    size_t pair_bytes = (size_t)nbuck * NREP * (size_t)cap_r * 8ull;
    size_t need = alloc_bytes + pair_bytes;          // ~144 MB

    if (ws_size >= need && nbuck <= NBUCK_PAD) {
        unsigned int* alloc = (unsigned int*)d_ws;
        unsigned long long* pairs = (unsigned long long*)((char*)d_ws + alloc_bytes);
        (void)hipMemsetAsync(alloc, 0, alloc_bytes, stream);

        int nt_tiles = (ne + TILE - 1) / TILE;       // 3907
        vu_partition<<<nt_tiles, TPB, 0, stream>>>(edges, eattr, pairs, alloc,
                                                   ne, nbuck, cap_r);
        vu_aggregate<<<nbuck, 1024, 0, stream>>>(pairs, alloc, vattr, out,
                                                 nv, cap_r);
    } else {
        int threads = 256;
        int blocks = (nv + threads - 1) / threads;
        vu_init_kernel<<<blocks, threads, 0, stream>>>(vattr, out, nv);
        int nt = (ne + 3) / 4;
        blocks = (nt + threads - 1) / threads;
        vu_scatter_kernel<<<blocks, threads, 0, stream>>>(edges, eattr, out, ne);
    }
}